// Round 16
// baseline (316.336 us; speedup 1.0000x reference)
//
#include <hip/hip_runtime.h>
#include <stdint.h>

#define NB 118
#define MSZ (118*118)
#define S 136   // fp16 elems per LDS row (272 B; 16B-aligned rows, ~2-way banks on reads)

typedef _Float16 f16x8 __attribute__((ext_vector_type(8)));
typedef _Float16 f16x4 __attribute__((ext_vector_type(4)));
typedef float f32x4 __attribute__((ext_vector_type(4)));

__device__ __forceinline__ f32x4 mfma16(f16x8 a, f16x8 b, f32x4 c) {
    return __builtin_amdgcn_mfma_f32_16x16x32_f16(a, b, c, 0, 0, 0);
}

// Pre-pack W1/W2 [320][64] f32 -> fp16 in MFMA B-fragment order:
// frag (t,c): lane l, j -> W[t*32 + (l>>4)*8 + j][c*16 + (l&15)]
__global__ __launch_bounds__(256) void prep_w(const float* __restrict__ W1,
                                              const float* __restrict__ W2,
                                              _Float16* __restrict__ WP)
{
    int g = blockIdx.x * 256 + threadIdx.x;
    if (g >= 5120) return;
    int wsel = g / 2560;
    int r = g % 2560;
    int t = r >> 8;
    int c = (r >> 6) & 3;
    int l = r & 63;
    const float* W = wsel ? W2 : W1;
    _Float16* dst = WP + wsel * 20480 + r * 8;
#pragma unroll
    for (int j = 0; j < 8; j++) {
        int kk = t * 32 + (l >> 4) * 8 + j;
        int col = c * 16 + (l & 15);
        dst[j] = (_Float16)W[kk * 64 + col];
    }
}

// Load the 4 A-fragments (one M row, all K) as fp16, with K-tail zeroing.
__device__ __forceinline__ void load_afrags(const float* __restrict__ M, int row,
                                            int lhi, f16x8 (&a)[4])
{
    const float* __restrict__ pr_ = M + row * NB;
#pragma unroll
    for (int t = 0; t < 4; t++) {
        int kb = t * 32 + lhi * 8;
        const float* p = pr_ + kb;
        float vv[8];
        if (t < 3) {
#pragma unroll
            for (int q = 0; q < 4; q++) {
                float2 u = *(const float2*)(p + 2 * q);
                vv[2 * q] = u.x; vv[2 * q + 1] = u.y;
            }
        } else {                          // K tail: cols >=118 are zero
#pragma unroll
            for (int q = 0; q < 4; q++) {
                int k0 = kb + 2 * q;
                if (k0 <= 116) {
                    float2 u = *(const float2*)(p + 2 * q);
                    vv[2 * q] = u.x; vv[2 * q + 1] = u.y;
                } else { vv[2 * q] = 0.f; vv[2 * q + 1] = 0.f; }
            }
        }
        f16x8 h;
#pragma unroll
        for (int j = 0; j < 8; j++) h[j] = (_Float16)vv[j];
        a[t] = h;
    }
}

// MFMA chain from preloaded A-frags: acc[c] += A @ EF  (B from LDS)
__device__ __forceinline__ void mfma_all(const f16x8 (&a)[4], const _Float16* SH_,
                                         int lane, f32x4 (&acc)[8])
{
    const int l15 = lane & 15, lhi = lane >> 4;
#pragma unroll
    for (int t = 0; t < 4; t++) {
#pragma unroll
        for (int c = 0; c < 8; c++) {
            f16x8 bfr = *(const f16x8*)&SH_[(c * 16 + l15) * S + t * 32 + lhi * 8];
            acc[c] = mfma16(a[t], bfr, acc[c]);
        }
    }
}

// Scale + write packed source into RT [row][128] (fp16). Per-wave rows only.
__device__ __forceinline__ void writeRT(_Float16* RT_, const f16x4 (&pE)[4],
                                        const f16x4 (&pF)[4],
                                        float sE, float sF, int w, int lane)
{
    const int l15 = lane & 15, lhi = lane >> 4;
    const _Float16 hE = (_Float16)sE, hF = (_Float16)sF;
#pragma unroll
    for (int c = 0; c < 4; c++)
#pragma unroll
        for (int r = 0; r < 4; r++) {
            int row = w * 16 + lhi * 4 + r;
            RT_[row * S + c * 16 + l15]      = pE[c][r] * hE;
            RT_[row * S + 64 + c * 16 + l15] = pF[c][r] * hF;
        }
}

// Stage-2 round j: VE += RT[:,0:64] @ W1-block, VF += RT[:,64:128] @ W2-block
__device__ __forceinline__ void s2round(const _Float16* RT_,
                                        const _Float16* __restrict__ W1P,
                                        const _Float16* __restrict__ W2P,
                                        int j, int w, int lane,
                                        f32x4 (&VE)[4], f32x4 (&VF)[4])
{
    const int l15 = lane & 15, lhi = lane >> 4;
    const int row = w * 16 + l15;
#pragma unroll
    for (int th = 0; th < 2; th++) {
        int t = 2 * j + th;
        int kk = th * 32 + lhi * 8;
        f16x8 ae = *(const f16x8*)&RT_[row * S + kk];
        f16x8 af = *(const f16x8*)&RT_[row * S + 64 + kk];
#pragma unroll
        for (int c = 0; c < 4; c++) {
            f16x8 bw1 = *(const f16x8*)&W1P[((t * 4 + c) * 64 + lane) * 8];
            f16x8 bw2 = *(const f16x8*)&W2P[((t * 4 + c) * 64 + lane) * 8];
            VE[c] = mfma16(ae, bw1, VE[c]);
            VF[c] = mfma16(af, bw2, VF[c]);
        }
    }
}

__global__ __launch_bounds__(512) __attribute__((amdgpu_waves_per_eu(2)))
void gcn_main(
    const float* __restrict__ E, const float* __restrict__ F,
    const float* __restrict__ K1, const float* __restrict__ K2,
    const float* __restrict__ Gn, const float* __restrict__ Bn,
    const float* __restrict__ Gdg, const float* __restrict__ Bdg,
    const float* __restrict__ Pdg, const float* __restrict__ Qdg,
    const float* __restrict__ b1, const float* __restrict__ b2,
    const float* __restrict__ wae, const float* __restrict__ bae,
    const float* __restrict__ waf, const float* __restrict__ baf,
    const _Float16* __restrict__ W1P, const _Float16* __restrict__ W2P,
    float* __restrict__ outE, float* __restrict__ outF)
{
    // SH serves as EFt [dim][node] before stage-2, then as RT [node][128].
    __shared__ __align__(16) _Float16 SH[128 * S];
    __shared__ float cs[8][64];   // col sums: 0 e3,1 new_e,2 e1,3 e2 | 4 f3,5 new_f,6 f1,7 f2
    __shared__ float sPd[128], sQd[128], sGd[128], sBd[128];

    const int b = blockIdx.x;
    const int tid = threadIdx.x;
    const int lane = tid & 63;
    const int w = tid >> 6;          // 8 waves, 16 rows each
    const int l15 = lane & 15;
    const int lhi = lane >> 4;
    const f32x4 Z4 = {0.f, 0.f, 0.f, 0.f};

    // ---- zero cs (512 floats) + pad-node tail of SH, stage diag ----
    ((float*)cs)[tid] = 0.0f;
    if (tid < 128) {
        f16x8 z8 = {};
        *(f16x8*)&SH[tid * S + 120] = z8;   // nodes 120..127 zero (K-tail)
    }
    if (tid < NB) {
        sPd[tid] = Pdg[b * NB + tid]; sQd[tid] = Qdg[b * NB + tid];
        sGd[tid] = Gdg[b * NB + tid]; sBd[tid] = Bdg[b * NB + tid];
    } else if (tid < 128) {
        sPd[tid] = 0.f; sQd[tid] = 0.f; sGd[tid] = 1.f; sBd[tid] = 1.f;
    }

    // ---- stage e,f -> SH transposed fp16 (node-quad packed ds_write_b64) ----
    const float* eb = E + (size_t)b * NB * 64;
    const float* fb = F + (size_t)b * NB * 64;
    for (int id = tid; id < 960; id += 512) {
        int m = id >= 480;
        int r = id - (m ? 480 : 0);
        int q = r >> 4;        // node quad 0..29
        int dq = r & 15;       // d quad
        const float* src = m ? fb : eb;
        int dbase = m ? 64 : 0;
        f32x4 v0, v1, v2, v3;
        int row = 4 * q;
        v0 = *(const f32x4*)(src + (row + 0) * 64 + dq * 4);
        v1 = *(const f32x4*)(src + (row + 1) * 64 + dq * 4);
        v2 = (row + 2 < NB) ? *(const f32x4*)(src + (row + 2) * 64 + dq * 4) : Z4;
        v3 = (row + 3 < NB) ? *(const f32x4*)(src + (row + 3) * 64 + dq * 4) : Z4;
#pragma unroll
        for (int j = 0; j < 4; j++) {
            f16x4 t = { (_Float16)v0[j], (_Float16)v1[j], (_Float16)v2[j], (_Float16)v3[j] };
            *(f16x4*)&SH[(dbase + dq * 4 + j) * S + 4 * q] = t;
        }
    }
    __syncthreads();   // S1: SH(EFt), cs, diag ready

    // ================= big parallel phase (no syncs inside) =================
    int arow = w * 16 + l15;
    if (arow > 117) arow = 117;      // clamp pad rows (outputs discarded)

    // G and B A-frags loaded TOGETHER (one exposed round-trip, not two)
    f16x8 aG[4], aB[4];
    load_afrags(Gn + (size_t)b * MSZ, arow, lhi, aG);
    load_afrags(Bn + (size_t)b * MSZ, arow, lhi, aB);

    f32x4 accA[8], accB_[8];
#pragma unroll
    for (int c = 0; c < 8; c++) { accA[c] = Z4; accB_[c] = Z4; }
    mfma_all(aG, SH, lane, accA);
    mfma_all(aB, SH, lane, accB_);

    // Prefetch K1 A-frags (reuse aG registers; dead after its MFMA chain) —
    // the loads fly while the VALU-heavy physics below executes.
    load_afrags(K1 + (size_t)b * MSZ, arow, lhi, aG);

    // physics -> p0 (e3|f3), p1 (new_e|new_f) packed fp16 + column sums
    f16x4 p0E[4], p0F[4], p1E[4], p1F[4];
#pragma unroll
    for (int c = 0; c < 4; c++) {
        float se3 = 0, sf3 = 0, sne = 0, snf = 0;
#pragma unroll
        for (int r = 0; r < 4; r++) {
            int row = w * 16 + lhi * 4 + r;
            int d = c * 16 + l15;
            float Ge = accA[c][r], Gf = accA[c + 4][r];
            float Be = accB_[c][r], Bf = accB_[c + 4][r];
            float ev = (float)SH[d * S + row];
            float fv = (float)SH[(64 + d) * S + row];
            float pd = sPd[row], qd = sQd[row], gd = sGd[row], bd = sBd[row];
            float ef2 = ev * ev + fv * fv;
            float ib = 1.0f / (ef2 + 0.1f);
            float alpha = (pd * ev + qd * fv) * ib - Ge - Bf;
            float beta  = (qd * ev - pd * fv) * ib + Gf + Bf;   // faithful: uses Bf
            float ibg = 1.0f / (gd * gd + bd * bd);
            float e3 = (alpha * gd + beta * bd) * ibg;
            float f3 = (beta * gd - alpha * bd) * ibg;
            float bs1 = Ge - Bf, bs2 = Gf + Be;
            float Pt = pd - ef2 * gd, Qt = qd + ef2 * bd;
            float ne = (Pt * bs1 + Qt * bs2) * ibg;
            float nf = (Pt * bs2 - Qt * bs1) * ibg;
            p0E[c][r] = (_Float16)e3; p0F[c][r] = (_Float16)f3;
            p1E[c][r] = (_Float16)ne; p1F[c][r] = (_Float16)nf;
            if (row < NB) { se3 += e3; sf3 += f3; sne += ne; snf += nf; }
        }
        se3 += __shfl_xor(se3, 16); se3 += __shfl_xor(se3, 32);
        sf3 += __shfl_xor(sf3, 16); sf3 += __shfl_xor(sf3, 32);
        sne += __shfl_xor(sne, 16); sne += __shfl_xor(sne, 32);
        snf += __shfl_xor(snf, 16); snf += __shfl_xor(snf, 32);
        if (lhi == 0) {
            atomicAdd(&cs[0][c * 16 + l15], se3);
            atomicAdd(&cs[4][c * 16 + l15], sf3);
            atomicAdd(&cs[1][c * 16 + l15], sne);
            atomicAdd(&cs[5][c * 16 + l15], snf);
        }
    }

    // K1 -> p2 (e1|f1), K2 -> p3 (e2|f2), with column sums (means = attn inputs)
    f16x4 p2E[4], p2F[4], p3E[4], p3F[4];
    {
        f32x4 accK[8];
#pragma unroll
        for (int c = 0; c < 8; c++) accK[c] = Z4;
        mfma_all(aG, SH, lane, accK);                       // K1 (prefetched)
        load_afrags(K2 + (size_t)b * MSZ, arow, lhi, aB);   // prefetch K2 under colsum VALU
#pragma unroll
        for (int c = 0; c < 4; c++) {
            float sE = 0, sF = 0;
#pragma unroll
            for (int r = 0; r < 4; r++) {
                int row = w * 16 + lhi * 4 + r;
                float ve = accK[c][r], vf = accK[c + 4][r];
                p2E[c][r] = (_Float16)ve; p2F[c][r] = (_Float16)vf;
                if (row < NB) { sE += ve; sF += vf; }
            }
            sE += __shfl_xor(sE, 16); sE += __shfl_xor(sE, 32);
            sF += __shfl_xor(sF, 16); sF += __shfl_xor(sF, 32);
            if (lhi == 0) {
                atomicAdd(&cs[2][c * 16 + l15], sE);
                atomicAdd(&cs[6][c * 16 + l15], sF);
            }
        }
#pragma unroll
        for (int c = 0; c < 8; c++) accK[c] = Z4;
        mfma_all(aB, SH, lane, accK);                       // K2 (prefetched)
#pragma unroll
        for (int c = 0; c < 4; c++) {
            float sE = 0, sF = 0;
#pragma unroll
            for (int r = 0; r < 4; r++) {
                int row = w * 16 + lhi * 4 + r;
                float ve = accK[c][r], vf = accK[c + 4][r];
                p3E[c][r] = (_Float16)ve; p3F[c][r] = (_Float16)vf;
                if (row < NB) { sE += ve; sF += vf; }
            }
            sE += __shfl_xor(sE, 16); sE += __shfl_xor(sE, 32);
            sF += __shfl_xor(sF, 16); sF += __shfl_xor(sF, 32);
            if (lhi == 0) {
                atomicAdd(&cs[3][c * 16 + l15], sE);
                atomicAdd(&cs[7][c * 16 + l15], sF);
            }
        }
    }
    __syncthreads();   // S2: cs complete; SH(EFt) no longer read -> becomes RT

    // ---- attention scalars (each wave computes all 8 redundantly; no sync) ----
    float sEs[4], sFs[4];
    {
        float wl_e = wae[lane], wl_f = waf[lane];
        float b_e = bae[0], b_f = baf[0];
        float aE[4], aF[4];
#pragma unroll
        for (int s2 = 0; s2 < 4; s2++) {
            float xe = cs[s2][lane] * wl_e;
            float xf = cs[4 + s2][lane] * wl_f;
#pragma unroll
            for (int m = 1; m < 64; m <<= 1) { xe += __shfl_xor(xe, m); xf += __shfl_xor(xf, m); }
            aE[s2] = 1.0f / (1.0f + __expf(-(xe * (1.0f / NB) + b_e)));
            aF[s2] = 1.0f / (1.0f + __expf(-(xf * (1.0f / NB) + b_f)));
        }
        float ebs = aE[0] + aE[1] + aE[2] + aE[3] + 1e-4f;
        float fbs = aF[0] + aF[1] + aF[2] + aF[3] + 1e-4f;
#pragma unroll
        for (int j = 0; j < 4; j++) { sEs[j] = aE[j] / ebs; sFs[j] = aF[j] / fbs; }
    }

    // ---- stage-2: sync-free (each wave round-trips its OWN 16 RT rows) ----
    f32x4 VE[4], VF[4];
#pragma unroll
    for (int c = 0; c < 4; c++) { VE[c] = Z4; VF[c] = Z4; }

    writeRT(SH, p0E, p0F, sEs[0], sFs[0], w, lane);
    s2round(SH, W1P, W2P, 0, w, lane, VE, VF);
    writeRT(SH, p1E, p1F, sEs[1], sFs[1], w, lane);
    s2round(SH, W1P, W2P, 1, w, lane, VE, VF);
    writeRT(SH, p2E, p2F, sEs[2], sFs[2], w, lane);
    s2round(SH, W1P, W2P, 2, w, lane, VE, VF);
    writeRT(SH, p3E, p3F, sEs[3], sFs[3], w, lane);
    s2round(SH, W1P, W2P, 3, w, lane, VE, VF);

    // ---- round 4: + e @ W1[256:320], + f @ W2[256:320]  (A direct from global) ----
#pragma unroll
    for (int th = 0; th < 2; th++) {
        int t = 8 + th;
        int row = w * 16 + l15;
        if (row > 117) row = 117;
        const float* pe = eb + row * 64 + th * 32 + lhi * 8;
        const float* pf = fb + row * 64 + th * 32 + lhi * 8;
        f32x4 q0 = *(const f32x4*)pe, q1 = *(const f32x4*)(pe + 4);
        f32x4 u0 = *(const f32x4*)pf, u1 = *(const f32x4*)(pf + 4);
        f16x8 ae, af;
#pragma unroll
        for (int jj = 0; jj < 4; jj++) {
            ae[jj] = (_Float16)q0[jj]; ae[4 + jj] = (_Float16)q1[jj];
            af[jj] = (_Float16)u0[jj]; af[4 + jj] = (_Float16)u1[jj];
        }
#pragma unroll
        for (int c = 0; c < 4; c++) {
            f16x8 bw1 = *(const f16x8*)&W1P[((t * 4 + c) * 64 + lane) * 8];
            f16x8 bw2 = *(const f16x8*)&W2P[((t * 4 + c) * 64 + lane) * 8];
            VE[c] = mfma16(ae, bw1, VE[c]);
            VF[c] = mfma16(af, bw2, VF[c]);
        }
    }

    // ---- epilogue: bias + relu + store ----
#pragma unroll
    for (int c = 0; c < 4; c++) {
        float bb1 = b1[c * 16 + l15];
        float bb2 = b2[c * 16 + l15];
#pragma unroll
        for (int r = 0; r < 4; r++) {
            int row = w * 16 + lhi * 4 + r;
            if (row < NB) {
                size_t o = ((size_t)b * NB + row) * 64 + c * 16 + l15;
                outE[o] = fmaxf(VE[c][r] + bb1, 0.0f);
                outF[o] = fmaxf(VF[c][r] + bb2, 0.0f);
            }
        }
    }
}

extern "C" void kernel_launch(void* const* d_in, const int* in_sizes, int n_in,
                              void* d_out, int out_size, void* d_ws, size_t ws_size,
                              hipStream_t stream)
{
    (void)in_sizes; (void)n_in; (void)out_size; (void)ws_size;
    const float* E   = (const float*)d_in[0];
    const float* F   = (const float*)d_in[1];
    const float* K1  = (const float*)d_in[2];
    const float* K2  = (const float*)d_in[3];
    const float* Gn  = (const float*)d_in[4];
    const float* Bn  = (const float*)d_in[5];
    const float* Gdg = (const float*)d_in[6];
    const float* Bdg = (const float*)d_in[7];
    const float* Pdg = (const float*)d_in[8];
    const float* Qdg = (const float*)d_in[9];
    const float* W1  = (const float*)d_in[10];
    const float* b1  = (const float*)d_in[11];
    const float* W2  = (const float*)d_in[12];
    const float* b2  = (const float*)d_in[13];
    const float* wae = (const float*)d_in[14];
    const float* bae = (const float*)d_in[15];
    const float* waf = (const float*)d_in[16];
    const float* baf = (const float*)d_in[17];

    _Float16* WP = (_Float16*)d_ws;           // 2 * 20480 fp16 = 80 KB
    float* outE = (float*)d_out;
    float* outF = outE + (size_t)2048 * NB * 64;

    prep_w<<<20, 256, 0, stream>>>(W1, W2, WP);
    gcn_main<<<2048, 512, 0, stream>>>(E, F, K1, K2, Gn, Bn, Gdg, Bdg, Pdg, Qdg,
                                       b1, b2, wae, bae, waf, baf,
                                       WP, WP + 20480, outE, outF);
}

// Round 17
// 277.494 us; speedup vs baseline: 1.1400x; 1.1400x over previous
//
#include <hip/hip_runtime.h>
#include <stdint.h>

#define NB 118
#define MSZ (118*118)          // 13924 floats = 55696 B per matrix
#define KCH 3584               // 16B chunks staged per matrix (rounded to 64*8)
#define KFL (KCH*4)            // 14336 floats (57344 B) per LDS K buffer
#define S 136   // fp16 elems per LDS row (272 B; 16B-aligned rows, ~2-way banks on reads)

typedef _Float16 f16x8 __attribute__((ext_vector_type(8)));
typedef _Float16 f16x4 __attribute__((ext_vector_type(4)));
typedef float f32x4 __attribute__((ext_vector_type(4)));

__device__ __forceinline__ f32x4 mfma16(f16x8 a, f16x8 b, f32x4 c) {
    return __builtin_amdgcn_mfma_f32_16x16x32_f16(a, b, c, 0, 0, 0);
}

// Pre-pack W1/W2 [320][64] f32 -> fp16 in MFMA B-fragment order:
// frag (t,c): lane l, j -> W[t*32 + (l>>4)*8 + j][c*16 + (l&15)]
__global__ __launch_bounds__(256) void prep_w(const float* __restrict__ W1,
                                              const float* __restrict__ W2,
                                              _Float16* __restrict__ WP)
{
    int g = blockIdx.x * 256 + threadIdx.x;
    if (g >= 5120) return;
    int wsel = g / 2560;
    int r = g % 2560;
    int t = r >> 8;
    int c = (r >> 6) & 3;
    int l = r & 63;
    const float* W = wsel ? W2 : W1;
    _Float16* dst = WP + wsel * 20480 + r * 8;
#pragma unroll
    for (int j = 0; j < 8; j++) {
        int kk = t * 32 + (l >> 4) * 8 + j;
        int col = c * 16 + (l & 15);
        dst[j] = (_Float16)W[kk * 64 + col];
    }
}

// Async-stage one 118x118 f32 matrix into LDS (zero VGPR held, vmcnt in flight).
// Wave w owns chunks [w*448, w*448+448); dest = wave-uniform base + lane*16.
__device__ __forceinline__ void prefetchK(const float* src, float* dst,
                                          int w, int lane)
{
#pragma unroll
    for (int i = 0; i < 7; i++) {
        int chunk = w * 448 + i * 64 + lane;
        int fidx = chunk * 4;
        if (fidx > MSZ - 4) fidx = MSZ - 4;          // clamp OOB reads (pad area, never consumed)
        const float* g = src + fidx;
        float* l = dst + (w * 448 + i * 64) * 4;     // wave-uniform LDS base
        __builtin_amdgcn_global_load_lds(
            (const __attribute__((address_space(1))) void*)g,
            (__attribute__((address_space(3))) void*)l,
            16, 0, 0);
    }
}

// Stage-1 matmul (8-wave): acc[c] += M[w-rows] @ EF  (A from LDS f32, B from LDS fp16)
__device__ __forceinline__ void stage1(const float* M,
                                       const _Float16* SH_, int w, int lane,
                                       f32x4 (&acc)[8])
{
    const int l15 = lane & 15, lhi = lane >> 4;
    int row = w * 16 + l15;
    if (row > 117) row = 117;            // clamp pad rows (outputs discarded)
    const float* pr_ = M + row * NB;
#pragma unroll
    for (int t = 0; t < 4; t++) {
        int kb = t * 32 + lhi * 8;
        const float* p = pr_ + kb;
        float vv[8];
        if (t < 3) {
#pragma unroll
            for (int q = 0; q < 4; q++) {
                float2 u = *(const float2*)(p + 2 * q);
                vv[2 * q] = u.x; vv[2 * q + 1] = u.y;
            }
        } else {                          // K tail: cols >=118 are zero
#pragma unroll
            for (int q = 0; q < 4; q++) {
                int k0 = kb + 2 * q;
                if (k0 <= 116) {
                    float2 u = *(const float2*)(p + 2 * q);
                    vv[2 * q] = u.x; vv[2 * q + 1] = u.y;
                } else { vv[2 * q] = 0.f; vv[2 * q + 1] = 0.f; }
            }
        }
        f16x8 a;
#pragma unroll
        for (int j = 0; j < 8; j++) a[j] = (_Float16)vv[j];
#pragma unroll
        for (int c = 0; c < 8; c++) {
            f16x8 bfr = *(const f16x8*)&SH_[(c * 16 + l15) * S + t * 32 + lhi * 8];
            acc[c] = mfma16(a, bfr, acc[c]);
        }
    }
}

// Scale + write packed source into RT [row][128] (fp16). Per-wave rows only.
__device__ __forceinline__ void writeRT(_Float16* RT_, const f16x4 (&pE)[4],
                                        const f16x4 (&pF)[4],
                                        float sE, float sF, int w, int lane)
{
    const int l15 = lane & 15, lhi = lane >> 4;
    const _Float16 hE = (_Float16)sE, hF = (_Float16)sF;
#pragma unroll
    for (int c = 0; c < 4; c++)
#pragma unroll
        for (int r = 0; r < 4; r++) {
            int row = w * 16 + lhi * 4 + r;
            RT_[row * S + c * 16 + l15]      = pE[c][r] * hE;
            RT_[row * S + 64 + c * 16 + l15] = pF[c][r] * hF;
        }
}

// Stage-2 round j: VE += RT[:,0:64] @ W1-block, VF += RT[:,64:128] @ W2-block
__device__ __forceinline__ void s2round(const _Float16* RT_,
                                        const _Float16* __restrict__ W1P,
                                        const _Float16* __restrict__ W2P,
                                        int j, int w, int lane,
                                        f32x4 (&VE)[4], f32x4 (&VF)[4])
{
    const int l15 = lane & 15, lhi = lane >> 4;
    const int row = w * 16 + l15;
#pragma unroll
    for (int th = 0; th < 2; th++) {
        int t = 2 * j + th;
        int kk = th * 32 + lhi * 8;
        f16x8 ae = *(const f16x8*)&RT_[row * S + kk];
        f16x8 af = *(const f16x8*)&RT_[row * S + 64 + kk];
#pragma unroll
        for (int c = 0; c < 4; c++) {
            f16x8 bw1 = *(const f16x8*)&W1P[((t * 4 + c) * 64 + lane) * 8];
            f16x8 bw2 = *(const f16x8*)&W2P[((t * 4 + c) * 64 + lane) * 8];
            VE[c] = mfma16(ae, bw1, VE[c]);
            VF[c] = mfma16(af, bw2, VF[c]);
        }
    }
}

__global__ __launch_bounds__(512, 2) void gcn_main(
    const float* __restrict__ E, const float* __restrict__ F,
    const float* __restrict__ K1, const float* __restrict__ K2,
    const float* __restrict__ Gn, const float* __restrict__ Bn,
    const float* __restrict__ Gdg, const float* __restrict__ Bdg,
    const float* __restrict__ Pdg, const float* __restrict__ Qdg,
    const float* __restrict__ b1, const float* __restrict__ b2,
    const float* __restrict__ wae, const float* __restrict__ bae,
    const float* __restrict__ waf, const float* __restrict__ baf,
    const _Float16* __restrict__ W1P, const _Float16* __restrict__ W2P,
    float* __restrict__ outE, float* __restrict__ outF)
{
    // SH serves as EFt [dim][node] before stage-2, then as RT [node][128].
    __shared__ __align__(16) _Float16 SH[128 * S];
    __shared__ __align__(16) float KAf[KFL];   // async-staged A matrices (G/K1)
    __shared__ __align__(16) float KBf[KFL];   // async-staged A matrices (B/K2)
    __shared__ float cs[8][64];   // col sums: 0 e3,1 new_e,2 e1,3 e2 | 4 f3,5 new_f,6 f1,7 f2
    __shared__ float sPd[128], sQd[128], sGd[128], sBd[128];

    const int b = blockIdx.x;
    const int tid = threadIdx.x;
    const int lane = tid & 63;
    const int w = tid >> 6;          // 8 waves, 16 rows each
    const int l15 = lane & 15;
    const int lhi = lane >> 4;
    const f32x4 Z4 = {0.f, 0.f, 0.f, 0.f};

    // ---- issue async G/B -> LDS immediately (fly under e/f staging) ----
    prefetchK(Gn + (size_t)b * MSZ, KAf, w, lane);
    prefetchK(Bn + (size_t)b * MSZ, KBf, w, lane);

    // ---- zero cs (512 floats) + pad-node tail of SH, stage diag ----
    ((float*)cs)[tid] = 0.0f;
    if (tid < 128) {
        f16x8 z8 = {};
        *(f16x8*)&SH[tid * S + 120] = z8;   // nodes 120..127 zero (K-tail)
    }
    if (tid < NB) {
        sPd[tid] = Pdg[b * NB + tid]; sQd[tid] = Qdg[b * NB + tid];
        sGd[tid] = Gdg[b * NB + tid]; sBd[tid] = Bdg[b * NB + tid];
    } else if (tid < 128) {
        sPd[tid] = 0.f; sQd[tid] = 0.f; sGd[tid] = 1.f; sBd[tid] = 1.f;
    }

    // ---- stage e,f -> SH transposed fp16 (node-quad packed ds_write_b64) ----
    const float* eb = E + (size_t)b * NB * 64;
    const float* fb = F + (size_t)b * NB * 64;
    for (int id = tid; id < 960; id += 512) {
        int m = id >= 480;
        int r = id - (m ? 480 : 0);
        int q = r >> 4;        // node quad 0..29
        int dq = r & 15;       // d quad
        const float* src = m ? fb : eb;
        int dbase = m ? 64 : 0;
        f32x4 v0, v1, v2, v3;
        int row = 4 * q;
        v0 = *(const f32x4*)(src + (row + 0) * 64 + dq * 4);
        v1 = *(const f32x4*)(src + (row + 1) * 64 + dq * 4);
        v2 = (row + 2 < NB) ? *(const f32x4*)(src + (row + 2) * 64 + dq * 4) : Z4;
        v3 = (row + 3 < NB) ? *(const f32x4*)(src + (row + 3) * 64 + dq * 4) : Z4;
#pragma unroll
        for (int j = 0; j < 4; j++) {
            f16x4 t = { (_Float16)v0[j], (_Float16)v1[j], (_Float16)v2[j], (_Float16)v3[j] };
            *(f16x4*)&SH[(dbase + dq * 4 + j) * S + 4 * q] = t;
        }
    }
    __syncthreads();   // S1: drains vmcnt -> G,B in LDS; SH(EFt), cs, diag ready

    // ---- G/B products from LDS ----
    f32x4 accA[8], accB_[8];
#pragma unroll
    for (int c = 0; c < 8; c++) { accA[c] = Z4; accB_[c] = Z4; }
    stage1(KAf, SH, w, lane, accA);
    stage1(KBf, SH, w, lane, accB_);
    __syncthreads();   // S1b: all waves done reading KA/KB -> safe to overwrite

    // ---- issue async K1/K2 -> LDS (fly under physics below) ----
    prefetchK(K1 + (size_t)b * MSZ, KAf, w, lane);
    prefetchK(K2 + (size_t)b * MSZ, KBf, w, lane);

    // physics -> p0 (e3|f3), p1 (new_e|new_f) packed fp16 + column sums
    f16x4 p0E[4], p0F[4], p1E[4], p1F[4];
#pragma unroll
    for (int c = 0; c < 4; c++) {
        float se3 = 0, sf3 = 0, sne = 0, snf = 0;
#pragma unroll
        for (int r = 0; r < 4; r++) {
            int row = w * 16 + lhi * 4 + r;
            int d = c * 16 + l15;
            float Ge = accA[c][r], Gf = accA[c + 4][r];
            float Be = accB_[c][r], Bf = accB_[c + 4][r];
            float ev = (float)SH[d * S + row];
            float fv = (float)SH[(64 + d) * S + row];
            float pd = sPd[row], qd = sQd[row], gd = sGd[row], bd = sBd[row];
            float ef2 = ev * ev + fv * fv;
            float ib = 1.0f / (ef2 + 0.1f);
            float alpha = (pd * ev + qd * fv) * ib - Ge - Bf;
            float beta  = (qd * ev - pd * fv) * ib + Gf + Bf;   // faithful: uses Bf
            float ibg = 1.0f / (gd * gd + bd * bd);
            float e3 = (alpha * gd + beta * bd) * ibg;
            float f3 = (beta * gd - alpha * bd) * ibg;
            float bs1 = Ge - Bf, bs2 = Gf + Be;
            float Pt = pd - ef2 * gd, Qt = qd + ef2 * bd;
            float ne = (Pt * bs1 + Qt * bs2) * ibg;
            float nf = (Pt * bs2 - Qt * bs1) * ibg;
            p0E[c][r] = (_Float16)e3; p0F[c][r] = (_Float16)f3;
            p1E[c][r] = (_Float16)ne; p1F[c][r] = (_Float16)nf;
            if (row < NB) { se3 += e3; sf3 += f3; sne += ne; snf += nf; }
        }
        se3 += __shfl_xor(se3, 16); se3 += __shfl_xor(se3, 32);
        sf3 += __shfl_xor(sf3, 16); sf3 += __shfl_xor(sf3, 32);
        sne += __shfl_xor(sne, 16); sne += __shfl_xor(sne, 32);
        snf += __shfl_xor(snf, 16); snf += __shfl_xor(snf, 32);
        if (lhi == 0) {
            atomicAdd(&cs[0][c * 16 + l15], se3);
            atomicAdd(&cs[4][c * 16 + l15], sf3);
            atomicAdd(&cs[1][c * 16 + l15], sne);
            atomicAdd(&cs[5][c * 16 + l15], snf);
        }
    }
    __syncthreads();   // S2a: drains vmcnt -> K1,K2 in LDS

    // K1 -> p2 (e1|f1), K2 -> p3 (e2|f2), with column sums (means = attn inputs)
    f16x4 p2E[4], p2F[4], p3E[4], p3F[4];
    {
        f32x4 accK[8];
#pragma unroll
        for (int c = 0; c < 8; c++) accK[c] = Z4;
        stage1(KAf, SH, w, lane, accK);
#pragma unroll
        for (int c = 0; c < 4; c++) {
            float sE = 0, sF = 0;
#pragma unroll
            for (int r = 0; r < 4; r++) {
                int row = w * 16 + lhi * 4 + r;
                float ve = accK[c][r], vf = accK[c + 4][r];
                p2E[c][r] = (_Float16)ve; p2F[c][r] = (_Float16)vf;
                if (row < NB) { sE += ve; sF += vf; }
            }
            sE += __shfl_xor(sE, 16); sE += __shfl_xor(sE, 32);
            sF += __shfl_xor(sF, 16); sF += __shfl_xor(sF, 32);
            if (lhi == 0) {
                atomicAdd(&cs[2][c * 16 + l15], sE);
                atomicAdd(&cs[6][c * 16 + l15], sF);
            }
        }
#pragma unroll
        for (int c = 0; c < 8; c++) accK[c] = Z4;
        stage1(KBf, SH, w, lane, accK);
#pragma unroll
        for (int c = 0; c < 4; c++) {
            float sE = 0, sF = 0;
#pragma unroll
            for (int r = 0; r < 4; r++) {
                int row = w * 16 + lhi * 4 + r;
                float ve = accK[c][r], vf = accK[c + 4][r];
                p3E[c][r] = (_Float16)ve; p3F[c][r] = (_Float16)vf;
                if (row < NB) { sE += ve; sF += vf; }
            }
            sE += __shfl_xor(sE, 16); sE += __shfl_xor(sE, 32);
            sF += __shfl_xor(sF, 16); sF += __shfl_xor(sF, 32);
            if (lhi == 0) {
                atomicAdd(&cs[3][c * 16 + l15], sE);
                atomicAdd(&cs[7][c * 16 + l15], sF);
            }
        }
    }
    __syncthreads();   // S2: cs complete; SH(EFt) no longer read -> becomes RT

    // ---- attention scalars (each wave computes all 8 redundantly; no sync) ----
    float sEs[4], sFs[4];
    {
        float wl_e = wae[lane], wl_f = waf[lane];
        float b_e = bae[0], b_f = baf[0];
        float aE[4], aF[4];
#pragma unroll
        for (int s2 = 0; s2 < 4; s2++) {
            float xe = cs[s2][lane] * wl_e;
            float xf = cs[4 + s2][lane] * wl_f;
#pragma unroll
            for (int m = 1; m < 64; m <<= 1) { xe += __shfl_xor(xe, m); xf += __shfl_xor(xf, m); }
            aE[s2] = 1.0f / (1.0f + __expf(-(xe * (1.0f / NB) + b_e)));
            aF[s2] = 1.0f / (1.0f + __expf(-(xf * (1.0f / NB) + b_f)));
        }
        float ebs = aE[0] + aE[1] + aE[2] + aE[3] + 1e-4f;
        float fbs = aF[0] + aF[1] + aF[2] + aF[3] + 1e-4f;
#pragma unroll
        for (int j = 0; j < 4; j++) { sEs[j] = aE[j] / ebs; sFs[j] = aF[j] / fbs; }
    }

    // ---- stage-2: sync-free (each wave round-trips its OWN 16 RT rows) ----
    f32x4 VE[4], VF[4];
#pragma unroll
    for (int c = 0; c < 4; c++) { VE[c] = Z4; VF[c] = Z4; }

    writeRT(SH, p0E, p0F, sEs[0], sFs[0], w, lane);
    s2round(SH, W1P, W2P, 0, w, lane, VE, VF);
    writeRT(SH, p1E, p1F, sEs[1], sFs[1], w, lane);
    s2round(SH, W1P, W2P, 1, w, lane, VE, VF);
    writeRT(SH, p2E, p2F, sEs[2], sFs[2], w, lane);
    s2round(SH, W1P, W2P, 2, w, lane, VE, VF);
    writeRT(SH, p3E, p3F, sEs[3], sFs[3], w, lane);
    s2round(SH, W1P, W2P, 3, w, lane, VE, VF);

    // ---- round 4: + e @ W1[256:320], + f @ W2[256:320]  (A direct from global) ----
#pragma unroll
    for (int th = 0; th < 2; th++) {
        int t = 8 + th;
        int row = w * 16 + l15;
        if (row > 117) row = 117;
        const float* pe = eb + row * 64 + th * 32 + lhi * 8;
        const float* pf = fb + row * 64 + th * 32 + lhi * 8;
        f32x4 q0 = *(const f32x4*)pe, q1 = *(const f32x4*)(pe + 4);
        f32x4 u0 = *(const f32x4*)pf, u1 = *(const f32x4*)(pf + 4);
        f16x8 ae, af;
#pragma unroll
        for (int jj = 0; jj < 4; jj++) {
            ae[jj] = (_Float16)q0[jj]; ae[4 + jj] = (_Float16)q1[jj];
            af[jj] = (_Float16)u0[jj]; af[4 + jj] = (_Float16)u1[jj];
        }
#pragma unroll
        for (int c = 0; c < 4; c++) {
            f16x8 bw1 = *(const f16x8*)&W1P[((t * 4 + c) * 64 + lane) * 8];
            f16x8 bw2 = *(const f16x8*)&W2P[((t * 4 + c) * 64 + lane) * 8];
            VE[c] = mfma16(ae, bw1, VE[c]);
            VF[c] = mfma16(af, bw2, VF[c]);
        }
    }

    // ---- epilogue: bias + relu + store ----
#pragma unroll
    for (int c = 0; c < 4; c++) {
        float bb1 = b1[c * 16 + l15];
        float bb2 = b2[c * 16 + l15];
#pragma unroll
        for (int r = 0; r < 4; r++) {
            int row = w * 16 + lhi * 4 + r;
            if (row < NB) {
                size_t o = ((size_t)b * NB + row) * 64 + c * 16 + l15;
                outE[o] = fmaxf(VE[c][r] + bb1, 0.0f);
                outF[o] = fmaxf(VF[c][r] + bb2, 0.0f);
            }
        }
    }
}

extern "C" void kernel_launch(void* const* d_in, const int* in_sizes, int n_in,
                              void* d_out, int out_size, void* d_ws, size_t ws_size,
                              hipStream_t stream)
{
    (void)in_sizes; (void)n_in; (void)out_size; (void)ws_size;
    const float* E   = (const float*)d_in[0];
    const float* F   = (const float*)d_in[1];
    const float* K1  = (const float*)d_in[2];
    const float* K2  = (const float*)d_in[3];
    const float* Gn  = (const float*)d_in[4];
    const float* Bn  = (const float*)d_in[5];
    const float* Gdg = (const float*)d_in[6];
    const float* Bdg = (const float*)d_in[7];
    const float* Pdg = (const float*)d_in[8];
    const float* Qdg = (const float*)d_in[9];
    const float* W1  = (const float*)d_in[10];
    const float* b1  = (const float*)d_in[11];
    const float* W2  = (const float*)d_in[12];
    const float* b2  = (const float*)d_in[13];
    const float* wae = (const float*)d_in[14];
    const float* bae = (const float*)d_in[15];
    const float* waf = (const float*)d_in[16];
    const float* baf = (const float*)d_in[17];

    _Float16* WP = (_Float16*)d_ws;           // 2 * 20480 fp16 = 80 KB
    float* outE = (float*)d_out;
    float* outF = outE + (size_t)2048 * NB * 64;

    prep_w<<<20, 256, 0, stream>>>(W1, W2, WP);
    gcn_main<<<2048, 512, 0, stream>>>(E, F, K1, K2, Gn, Bn, Gdg, Bdg, Pdg, Qdg,
                                       b1, b2, wae, bae, waf, baf,
                                       WP, WP + 20480, outE, outF);
}